// Round 5
// baseline (142.485 us; speedup 1.0000x reference)
//
#include <hip/hip_runtime.h>
#include <math.h>

// ThrusterLag: y[k] = a*y[k-1] + (1-a)*tanh(2*deadzone((u-7.5)/2.5)), y[-1]=u_nl[0]
// a = exp(-DT/tau), tau = softplus(tau_param) + TAU_MIN, per channel (C=8).
// Shapes: u_seq (512, 8192, 8) f32; out same.
//
// Single-pass design (268 MB total HBM traffic):
//   one block per batch row; 512 threads; 4 tiles of 2048 steps.
//   Per tile: thread t owns steps [t*4, t*4+4) x 8ch (128B contiguous load),
//   computes zero-seeded local scan l[i][c] in registers. Linearity gives
//   y_i = l_i + a^{i+1} * C_t, where C_t (carry into thread t) comes from a
//   wave shuffle-scan + 8-wave LDS Horner prefix + closed-form row carry
//   (a^d computed by repeated squaring; terms underflow harmlessly).

typedef float v4f __attribute__((ext_vector_type(4)));

constexpr int kB    = 512;
constexpr int kL    = 8192;
constexpr int kC    = 8;
constexpr int kT    = 512;            // threads per block (8 waves)
constexpr int kSEG  = 4;              // steps per thread per tile
constexpr int kTile = kT * kSEG;      // 2048 steps per tile
constexpr int kNT   = kL / kTile;     // 4 tiles per row

constexpr float kDT     = 0.01f;
constexpr float kTauMin = 0.01f;

__device__ __forceinline__ float softplus_f(float p) {
    return fmaxf(p, 0.0f) + log1pf(__expf(-fabsf(p)));
}

// tanh(2 * deadzone((u - 7.5)/2.5))
__device__ __forceinline__ float u_nl(float u) {
    float uu = (u - 7.5f) * 0.4f;
    float ud = copysignf(fmaxf(fabsf(uu) - 0.05f, 0.0f), uu);
    float e = __expf(4.0f * ud);                    // 4*ud in [-3.8, 3.8]
    return (e - 1.0f) * __builtin_amdgcn_rcpf(e + 1.0f);
}

__global__ __launch_bounds__(kT, 4) void scan_row(const float* __restrict__ u,
                                                  const float* __restrict__ tp,
                                                  float* __restrict__ out) {
    const int row  = blockIdx.x;
    const int t    = threadIdx.x;
    const int lane = t & 63;
    const int w    = t >> 6;          // wave id 0..7

    // per-channel coefficients and per-thread decay factors
    float a[kC], oma[kC], D[kC], S[kC];
    #pragma unroll
    for (int c = 0; c < kC; ++c) {
        float tau = softplus_f(tp[c]) + kTauMin;
        float lna = -kDT / tau;                        // ln(a) < 0
        a[c]   = __expf(lna);
        oma[c] = 1.0f - a[c];
        D[c]   = __expf(lna * (float)(kSEG * lane));   // a^(SEG*lane)
        S[c]   = __expf(lna * (float)(kSEG * t));      // a^(SEG*t)
    }

    const float* base  = u   + (size_t)row * kL * kC;
    float*       obase = out + (size_t)row * kL * kC;

    // row carry R = y[-1] = u_nl(u[row, 0, :]) (broadcast load)
    float R[kC];
    {
        v4f q0 = *(const v4f*)(base);
        v4f q1 = *(const v4f*)(base + 4);
        R[0] = u_nl(q0.x); R[1] = u_nl(q0.y); R[2] = u_nl(q0.z); R[3] = u_nl(q0.w);
        R[4] = u_nl(q1.x); R[5] = u_nl(q1.y); R[6] = u_nl(q1.z); R[7] = u_nl(q1.w);
    }

    __shared__ float Tlds[2][8][kC];   // [slot][wave][ch] wave totals

    for (int tile = 0; tile < kNT; ++tile) {
        const float* tb = base + ((size_t)tile * kTile + (size_t)t * kSEG) * kC;

        // ---- load + zero-seeded local scan (all in registers) ----
        float l[kSEG][kC];
        float run[kC];
        #pragma unroll
        for (int c = 0; c < kC; ++c) run[c] = 0.0f;
        #pragma unroll
        for (int i = 0; i < kSEG; ++i) {
            v4f x0 = *(const v4f*)(tb + i * kC);
            v4f x1 = *(const v4f*)(tb + i * kC + 4);
            float v[kC] = {x0.x, x0.y, x0.z, x0.w, x1.x, x1.y, x1.z, x1.w};
            #pragma unroll
            for (int c = 0; c < kC; ++c) {
                run[c] = a[c] * run[c] + oma[c] * u_nl(v[c]);
                l[i][c] = run[c];
            }
        }

        // ---- wave inclusive scan of thread totals; M squares each round ----
        float I[kC], M[kC];
        #pragma unroll
        for (int c = 0; c < kC; ++c) {
            I[c] = run[c];
            float a2 = a[c] * a[c];
            M[c] = a2 * a2;                     // a^SEG (SEG=4)
        }
        #pragma unroll
        for (int d = 1; d < 64; d <<= 1) {
            #pragma unroll
            for (int c = 0; c < kC; ++c) {
                float up = __shfl_up(I[c], (unsigned)d, 64);
                if (lane >= d) I[c] += M[c] * up;
            }
            #pragma unroll
            for (int c = 0; c < kC; ++c) M[c] *= M[c];
        }
        // after 6 rounds: M = a^(SEG*64) = a^256

        // ---- publish wave totals, cross-wave Horner prefix ----
        if (lane == 63) {
            #pragma unroll
            for (int c = 0; c < kC; ++c) Tlds[tile & 1][w][c] = I[c];
        }
        __syncthreads();

        float E[kC];                            // wave-exclusive prefix
        #pragma unroll
        for (int c = 0; c < kC; ++c) {
            float e = __shfl_up(I[c], 1u, 64);
            E[c] = (lane == 0) ? 0.0f : e;
        }

        float P[kC], Tot[kC];
        #pragma unroll
        for (int c = 0; c < kC; ++c) { P[c] = 0.0f; Tot[c] = 0.0f; }
        #pragma unroll
        for (int j = 0; j < 8; ++j) {
            #pragma unroll
            for (int c = 0; c < kC; ++c) {
                float Tj = Tlds[tile & 1][j][c];
                Tot[c] = M[c] * Tot[c] + Tj;
                if (j < w) P[c] = M[c] * P[c] + Tj;   // wave-uniform branch
            }
        }

        // ---- carry into this thread; advance row carry ----
        float cy[kC];
        #pragma unroll
        for (int c = 0; c < kC; ++c) {
            float C = E[c] + D[c] * P[c] + S[c] * R[c];
            cy[c] = a[c] * C;                   // a^1 * C
            float m2 = M[c] * M[c];
            float m8 = m2 * m2; m8 = m8 * m8;   // a^2048 = tile decay
            R[c] = Tot[c] + m8 * R[c];
        }

        // ---- emit y_i = l_i + a^{i+1} C (128B contiguous per thread) ----
        float* ob = obase + ((size_t)tile * kTile + (size_t)t * kSEG) * kC;
        #pragma unroll
        for (int i = 0; i < kSEG; ++i) {
            v4f y0 = (v4f){l[i][0] + cy[0], l[i][1] + cy[1],
                           l[i][2] + cy[2], l[i][3] + cy[3]};
            v4f y1 = (v4f){l[i][4] + cy[4], l[i][5] + cy[5],
                           l[i][6] + cy[6], l[i][7] + cy[7]};
            *(v4f*)(ob + i * kC)     = y0;
            *(v4f*)(ob + i * kC + 4) = y1;
            if (i < kSEG - 1) {
                #pragma unroll
                for (int c = 0; c < kC; ++c) cy[c] *= a[c];
            }
        }
    }
}

extern "C" void kernel_launch(void* const* d_in, const int* in_sizes, int n_in,
                              void* d_out, int out_size, void* d_ws, size_t ws_size,
                              hipStream_t stream) {
    const float* u  = (const float*)d_in[0];
    const float* tp = (const float*)d_in[1];
    float* out = (float*)d_out;

    scan_row<<<kB, kT, 0, stream>>>(u, tp, out);
}

// Round 6
// 72.640 us; speedup vs baseline: 1.9615x; 1.9615x over previous
//
#include <hip/hip_runtime.h>
#include <math.h>

// ThrusterLag: y[k] = a*y[k-1] + (1-a)*tanh(2*deadzone((u-7.5)/2.5)), y[-1]=u_nl[0]
// a = exp(-DT/tau), tau = softplus(tau_param) + TAU_MIN, per channel (C=8).
// Shapes: u_seq (512, 8192, 8) f32; out same. Traffic floor: 268 MB.
//
// Single-pass: one block per row, 512 threads, 8 tiles of 1024 steps.
// Thread t owns 2 steps x 8 ch (64B contiguous). Zero-seeded local scan in
// registers; carry via wave shuffle-scan (multiplier squares a^2 -> a^128) +
// 8-wave LDS Horner; y_i = l_i + a^{i+1}*C. Row carry advances in closed form
// (a^1024 = (M^4)^2). R5 lesson: keep live state ~110 floats so the allocator
// stays <=128 VGPR (2 blocks/CU) with NO scratch spills (R5: VGPR=64 + 84MB
// spill traffic each way).

typedef float v4f __attribute__((ext_vector_type(4)));

constexpr int kB    = 512;
constexpr int kL    = 8192;
constexpr int kC    = 8;
constexpr int kT    = 512;            // threads per block (8 waves)
constexpr int kSEG  = 2;              // steps per thread per tile
constexpr int kTile = kT * kSEG;      // 1024 steps per tile
constexpr int kNT   = kL / kTile;     // 8 tiles per row

constexpr float kDT     = 0.01f;
constexpr float kTauMin = 0.01f;

__device__ __forceinline__ float softplus_f(float p) {
    return fmaxf(p, 0.0f) + log1pf(__expf(-fabsf(p)));
}

// tanh(2 * deadzone((u - 7.5)/2.5))
__device__ __forceinline__ float u_nl(float u) {
    float uu = (u - 7.5f) * 0.4f;
    float ud = copysignf(fmaxf(fabsf(uu) - 0.05f, 0.0f), uu);
    float e = __expf(4.0f * ud);                    // 4*ud in [-3.8, 3.8]
    return (e - 1.0f) * __builtin_amdgcn_rcpf(e + 1.0f);
}

__global__ __launch_bounds__(kT, 2) void scan_row(const float* __restrict__ u,
                                                  const float* __restrict__ tp,
                                                  float* __restrict__ out) {
    const int row  = blockIdx.x;
    const int t    = threadIdx.x;
    const int lane = t & 63;
    const int w    = t >> 6;          // wave id 0..7

    float a[kC], oma[kC], D[kC], R[kC];
    #pragma unroll
    for (int c = 0; c < kC; ++c) {
        float tau = softplus_f(tp[c]) + kTauMin;
        float lna = -kDT / tau;                        // ln(a) < 0
        a[c]   = __expf(lna);
        oma[c] = 1.0f - a[c];
        D[c]   = __expf(lna * (float)(kSEG * lane));   // a^(SEG*lane)
    }

    const float* base  = u   + (size_t)row * kL * kC;
    float*       obase = out + (size_t)row * kL * kC;

    // row carry R = y[-1] = u_nl(u[row, 0, :])
    {
        v4f q0 = *(const v4f*)(base);
        v4f q1 = *(const v4f*)(base + 4);
        R[0] = u_nl(q0.x); R[1] = u_nl(q0.y); R[2] = u_nl(q0.z); R[3] = u_nl(q0.w);
        R[4] = u_nl(q1.x); R[5] = u_nl(q1.y); R[6] = u_nl(q1.z); R[7] = u_nl(q1.w);
    }

    __shared__ float Tlds[2][8][kC];   // [slot][wave][ch] wave totals

    // prefetch tile 0 (thread's 64B: 4 x v4f)
    const float* tb = base + (size_t)t * kSEG * kC;
    v4f x0 = *(const v4f*)(tb);
    v4f x1 = *(const v4f*)(tb + 4);
    v4f x2 = *(const v4f*)(tb + 8);
    v4f x3 = *(const v4f*)(tb + 12);

    for (int tile = 0; tile < kNT; ++tile) {
        // ---- local zero-seeded scan of this thread's 2 steps ----
        float l0[kC], l1[kC];
        {
            float v0[kC] = {x0.x, x0.y, x0.z, x0.w, x1.x, x1.y, x1.z, x1.w};
            float v1[kC] = {x2.x, x2.y, x2.z, x2.w, x3.x, x3.y, x3.z, x3.w};
            #pragma unroll
            for (int c = 0; c < kC; ++c) {
                l0[c] = oma[c] * u_nl(v0[c]);
                l1[c] = a[c] * l0[c] + oma[c] * u_nl(v1[c]);
            }
        }

        // ---- issue next tile's loads early (hide HBM under scan phase) ----
        if (tile + 1 < kNT) {
            const float* nb = base + ((size_t)(tile + 1) * kTile + (size_t)t * kSEG) * kC;
            x0 = *(const v4f*)(nb);
            x1 = *(const v4f*)(nb + 4);
            x2 = *(const v4f*)(nb + 8);
            x3 = *(const v4f*)(nb + 12);
        }

        // ---- wave inclusive shuffle-scan of thread totals (mult squares) ----
        float I[kC], M[kC];
        #pragma unroll
        for (int c = 0; c < kC; ++c) {
            I[c] = l1[c];
            M[c] = a[c] * a[c];               // a^SEG (SEG=2)
        }
        #pragma unroll
        for (int d = 1; d < 64; d <<= 1) {
            #pragma unroll
            for (int c = 0; c < kC; ++c) {
                float up = __shfl_up(I[c], (unsigned)d, 64);
                if (lane >= d) I[c] += M[c] * up;
            }
            #pragma unroll
            for (int c = 0; c < kC; ++c) M[c] *= M[c];
        }
        // now M = a^(SEG*64) = a^128

        // ---- publish wave totals ----
        if (lane == 63) {
            #pragma unroll
            for (int c = 0; c < kC; ++c) Tlds[tile & 1][w][c] = I[c];
        }
        __syncthreads();

        // same-wave exclusive carry
        float E[kC];
        #pragma unroll
        for (int c = 0; c < kC; ++c) {
            float e = __shfl_up(I[c], 1u, 64);
            E[c] = (lane == 0) ? 0.0f : e;
        }

        // cross-wave Horner: P = prefix over waves j<w, Tot = all 8 waves
        float acc[kC], P[kC];
        #pragma unroll
        for (int c = 0; c < kC; ++c) { acc[c] = 0.0f; P[c] = 0.0f; }
        #pragma unroll
        for (int j = 0; j < 8; ++j) {
            #pragma unroll
            for (int c = 0; c < kC; ++c) {
                acc[c] = M[c] * acc[c] + Tlds[tile & 1][j][c];
                if (j == w - 1) P[c] = acc[c];   // wave-uniform select
            }
        }

        // ---- carry into this thread; emit; advance row carry ----
        float* ob = obase + ((size_t)tile * kTile + (size_t)t * kSEG) * kC;
        v4f y0a, y0b, y1a, y1b;
        #pragma unroll
        for (int c = 0; c < kC; ++c) {
            // Mw = M^w (w uniform, 3 bits); S = D * Mw
            float m2 = M[c] * M[c], m4 = m2 * m2;
            float Mw = 1.0f;
            if (w & 1) Mw *= M[c];
            if (w & 2) Mw *= m2;
            if (w & 4) Mw *= m4;
            float C  = E[c] + D[c] * (P[c] + Mw * R[c]);
            float cy = a[c] * C;
            float y0 = l0[c] + cy;
            float y1 = l1[c] + cy * a[c];
            if (c < 4) { y0a[c] = y0; y1a[c] = y1; }
            else       { y0b[c - 4] = y0; y1b[c - 4] = y1; }
            R[c] = acc[c] + (m4 * m4) * R[c];    // Tot + a^1024 * R
        }
        *(v4f*)(ob)      = y0a;
        *(v4f*)(ob + 4)  = y0b;
        *(v4f*)(ob + 8)  = y1a;
        *(v4f*)(ob + 12) = y1b;
    }
}

extern "C" void kernel_launch(void* const* d_in, const int* in_sizes, int n_in,
                              void* d_out, int out_size, void* d_ws, size_t ws_size,
                              hipStream_t stream) {
    const float* u  = (const float*)d_in[0];
    const float* tp = (const float*)d_in[1];
    float* out = (float*)d_out;

    scan_row<<<kB, kT, 0, stream>>>(u, tp, out);
}